// Round 11
// baseline (57.959 us; speedup 1.0000x reference)
//
#include <hip/hip_runtime.h>
#include <hip/hip_bf16.h>
#include <math.h>

#define BATCH 4096
#define NROWS 8192
#define DIM 256
#define NBLK2 1056                    // sum over Q of 2(Q+1), Q=0..31
#define NPIECE 64

// zn scale c with c^2 = 2*log2(e): sim_scaled = c^2*cos = 2*log2e*cos,
// so exp2(sim_scaled) = e^{2 cos} directly.
#define ZN_SCALE 1.698643600577466f   // sqrt(2.8853900817779268)
#define LN2F 0.6931471805599453f

typedef __attribute__((ext_vector_type(4))) float f32x4;
typedef __attribute__((ext_vector_type(16))) float f32x16;
typedef __attribute__((ext_vector_type(8))) short short8;

#if defined(__has_builtin)
#if __has_builtin(__builtin_amdgcn_exp2f)
#define EXP2F(x) __builtin_amdgcn_exp2f(x)
#endif
#endif
#ifndef EXP2F
#define EXP2F(x) __expf(LN2F * (x))
#endif

static __device__ __forceinline__ unsigned short f2bf(float x) {
    __hip_bfloat16 h = __float2bfloat16(x);
    return *reinterpret_cast<unsigned short*>(&h);
}
static __device__ __forceinline__ float bf2f(unsigned short u) {
    union { unsigned int i; float f; } x;
    x.i = ((unsigned int)u) << 16;
    return x.f;
}

// ---------------------------------------------------------------------------
// Kernel A: concat + L2-normalize + scale; write row-major (zn) AND
// 32x32x16-MFMA-fragment-packed (pk2) layouts.
// pk2 granule = one (32-row x 16-k) fragment = 1 KB, lane order for
// v_mfma_f32_32x32x16_bf16: lane = (k>>3)*32 + (row&31), elems k%8.
// Granule index G = (row>>5)*16 + (e>>4).
// ---------------------------------------------------------------------------
__global__ void normalize_kernel(const float* __restrict__ z_i,
                                 const float* __restrict__ z_j,
                                 unsigned short* __restrict__ zn,
                                 unsigned short* __restrict__ pk2) {
    int wid  = (blockIdx.x * blockDim.x + threadIdx.x) >> 6;   // row
    int lane = threadIdx.x & 63;
    if (wid >= NROWS) return;
    const float* src = (wid < BATCH) ? (z_i + (size_t)wid * DIM)
                                     : (z_j + (size_t)(wid - BATCH) * DIM);
    float4 v = reinterpret_cast<const float4*>(src)[lane];
    float ss = v.x * v.x + v.y * v.y + v.z * v.z + v.w * v.w;
#pragma unroll
    for (int m = 1; m < 64; m <<= 1) ss += __shfl_xor(ss, m);
    float inv = ZN_SCALE / fmaxf(sqrtf(ss), 1e-8f);
    ushort4 o;
    o.x = f2bf(v.x * inv);
    o.y = f2bf(v.y * inv);
    o.z = f2bf(v.z * inv);
    o.w = f2bf(v.w * inv);
    reinterpret_cast<ushort4*>(zn + (size_t)wid * DIM)[lane] = o;
    // lane handles e = 4*lane .. 4*lane+3
    size_t off = ((size_t)(wid >> 5) * 16 + (lane >> 2)) * 1024
               + (size_t)(((lane >> 1) & 1) * 32 + (wid & 31)) * 16
               + (size_t)(lane & 1) * 8;
    *reinterpret_cast<ushort4*>((char*)pk2 + off) = o;
}

// ---------------------------------------------------------------------------
// Kernel B: symmetric fused sim-GEMM + sum-of-exp, 32x32x16 MFMA, no LDS.
// Tiles: (p: 128-row panel 0..63) x (Q: 256-col panel 0..31), Q >= p>>1.
// t = Q(Q+1) + p, p in [0, 2Q+2) -> 1056 tiles; XCD swizzle 8x132.
// Block = 4 waves (wr: 64-row half, wc: 128-col half); wave = 64x128 via
// acc[2][4] f32x16. Fragments straight from pk2, 3-buffer 2-deep prefetch.
// Odd-p diagonal tile: wc=0 half is strictly-lower -> those waves exit.
// Denominators, each slot written EXACTLY ONCE (no collisions):
//   row-pieces: part [colpanel][rows of panel p]       (one wave per slot)
//   col-pieces: part2[p][wr][cols of colpanel]         (wr-split bank)
// Row r (panel pr) coverage: part slots [pr,64) + part2 ids [0,pr) x {wr}.
// ---------------------------------------------------------------------------
__global__ __launch_bounds__(256, 2)
void simloss_kernel(const unsigned short* __restrict__ pk2,
                    float* __restrict__ part  /* [NPIECE][NROWS]   */,
                    float* __restrict__ part2 /* [NPIECE][2][NROWS]*/) {
    int wave = threadIdx.x >> 6;
    int lane = threadIdx.x & 63;
    int wr = wave >> 1, wc = wave & 1;
    // XCD-contiguous bijective swizzle: 1056 = 8 x 132
    int b = (int)blockIdx.x;
    int t = (b & 7) * 132 + (b >> 3);
    int Q = (int)((sqrtf(4.0f * (float)t + 1.0f) - 1.0f) * 0.5f);
    while ((Q + 1) * (Q + 2) <= t) ++Q;
    while (Q * (Q + 1) > t) --Q;
    int p = t - Q * (Q + 1);

    int colpanel = 2 * Q + wc;
    if (colpanel < p) return;            // strictly-lower half of odd-p diag tile
    bool isdiag = (colpanel == p);

    const char* pkb = (const char*)pk2;
    size_t lane16 = (size_t)lane * 16;
    const char* Abase = pkb + (size_t)(4 * p + 2 * wr) * 16384 + lane16;
    const char* Bbase = pkb + (size_t)(8 * Q + 4 * wc) * 16384 + lane16;

    f32x16 acc[2][4];
#pragma unroll
    for (int m = 0; m < 2; ++m)
#pragma unroll
        for (int n = 0; n < 4; ++n)
#pragma unroll
            for (int r = 0; r < 16; ++r) acc[m][n][r] = 0.f;

    // K = 256 = 16 slices of 16; 3-buffer, 2-deep prefetch, fully unrolled.
    short8 Ab[3][2], Bb[3][4];
#pragma unroll
    for (int s0 = 0; s0 < 2; ++s0) {
#pragma unroll
        for (int m = 0; m < 2; ++m)
            Ab[s0][m] = *(const short8*)(Abase + (size_t)(m * 16 + s0) * 1024);
#pragma unroll
        for (int n = 0; n < 4; ++n)
            Bb[s0][n] = *(const short8*)(Bbase + (size_t)(n * 16 + s0) * 1024);
    }
#pragma unroll
    for (int s = 0; s < 16; ++s) {
        const int nb = (s + 2) % 3, cb = s % 3;
        if (s < 14) {
#pragma unroll
            for (int m = 0; m < 2; ++m)
                Ab[nb][m] = *(const short8*)(Abase + (size_t)(m * 16 + s + 2) * 1024);
#pragma unroll
            for (int n = 0; n < 4; ++n)
                Bb[nb][n] = *(const short8*)(Bbase + (size_t)(n * 16 + s + 2) * 1024);
        }
#pragma unroll
        for (int m = 0; m < 2; ++m)
#pragma unroll
            for (int n = 0; n < 4; ++n)
                acc[m][n] = __builtin_amdgcn_mfma_f32_32x32x16_bf16(
                    Ab[cb][m], Bb[cb][n], acc[m][n], 0, 0, 0);
    }

    // ---- epilogue: exp2, diag-zero, row sums + (strictly-upper) col sums
    // C/D layout (m74-verified): col = lane&31, row = (reg&3)+8*(reg>>2)+4*(lane>>5)
    int R0 = 128 * p + 64 * wr;
    int C0 = 256 * Q + 128 * wc;
    float cacc[4] = {0.f, 0.f, 0.f, 0.f};
#pragma unroll
    for (int m = 0; m < 2; ++m) {
        float dacc[16];
#pragma unroll
        for (int r = 0; r < 16; ++r) dacc[r] = 0.f;
#pragma unroll
        for (int n = 0; n < 4; ++n) {
            bool dz = isdiag && (n == 2 * wr + m);   // fragment on the diagonal
#pragma unroll
            for (int r = 0; r < 16; ++r) {
                float e = EXP2F(acc[m][n][r]);
                if (dz) {
                    int rowm = (r & 3) + 8 * (r >> 2) + 4 * (lane >> 5);
                    if (rowm == (lane & 31)) e = 0.0f;
                }
                dacc[r] += e;
                cacc[n] += e;
            }
        }
        // row-sums: reduce over the 32 col-lanes within each lane-half
#pragma unroll
        for (int r = 0; r < 16; ++r) {
            float v = dacc[r];
            v += __shfl_xor(v, 1);
            v += __shfl_xor(v, 2);
            v += __shfl_xor(v, 4);
            v += __shfl_xor(v, 8);
            v += __shfl_xor(v, 16);
            if ((lane & 31) == 0)
                part[(size_t)colpanel * NROWS + R0 + 32 * m
                     + (r & 3) + 8 * (r >> 2) + 4 * (lane >> 5)] = v;
        }
    }
    if (!isdiag) {                        // col pieces only for strictly-upper
#pragma unroll
        for (int n = 0; n < 4; ++n) {
            float c = cacc[n];
            c += __shfl_xor(c, 32);       // combine the two row-quarters
            if (lane < 32)                // per-(p,wr) bank: no collision
                part2[((size_t)p * 2 + wr) * NROWS + C0 + 32 * n + lane] = c;
        }
    }
}

// ---------------------------------------------------------------------------
// Kernel C: per-row loss: log(sum of pieces) - pos_dot*ln2
// Row r (panel pr): lanes < pr read part2[lane][0]+part2[lane][1];
// lanes >= pr read part[lane]. One row per wave.
// ---------------------------------------------------------------------------
__global__ void rowloss_kernel(const unsigned short* __restrict__ zn,
                               const float* __restrict__ part,
                               const float* __restrict__ part2,
                               float* __restrict__ cpart /* [NROWS] */) {
    int wave = threadIdx.x >> 6;
    int lane = threadIdx.x & 63;
    int r = blockIdx.x * 4 + wave;
    int pr = r >> 7;
    ushort4 za = reinterpret_cast<const ushort4*>(zn + (size_t)r * DIM)[lane];
    ushort4 zb = reinterpret_cast<const ushort4*>(zn + (size_t)(r ^ BATCH) * DIM)[lane];
    float dot = bf2f(za.x) * bf2f(zb.x) + bf2f(za.y) * bf2f(zb.y) +
                bf2f(za.z) * bf2f(zb.z) + bf2f(za.w) * bf2f(zb.w);
#pragma unroll
    for (int m = 1; m < 64; m <<= 1) dot += __shfl_xor(dot, m);
    float den;
    if (lane < pr)
        den = part2[((size_t)lane * 2 + 0) * NROWS + r]
            + part2[((size_t)lane * 2 + 1) * NROWS + r];
    else
        den = part[(size_t)lane * NROWS + r];
#pragma unroll
    for (int m = 1; m < 64; m <<= 1) den += __shfl_xor(den, m);
    if (lane == 0) cpart[r] = logf(den) - dot * LN2F;
}

// ---------------------------------------------------------------------------
// Kernel D: final reduction of 8192 row losses -> scalar loss / n
// ---------------------------------------------------------------------------
__global__ void final_kernel(const float* __restrict__ cpart,
                             float* __restrict__ out) {
    int lane = threadIdx.x & 63;
    int wave = threadIdx.x >> 6;
    double v = 0.0;
#pragma unroll
    for (int k = 0; k < 32; ++k)
        v += (double)cpart[threadIdx.x + k * 256];
#pragma unroll
    for (int m = 1; m < 64; m <<= 1) v += __shfl_xor(v, m);
    __shared__ double red[4];
    if (lane == 0) red[wave] = v;
    __syncthreads();
    if (threadIdx.x == 0)
        out[0] = (float)((red[0] + red[1] + red[2] + red[3]) / (double)NROWS);
}

// ---------------------------------------------------------------------------
extern "C" void kernel_launch(void* const* d_in, const int* in_sizes, int n_in,
                              void* d_out, int out_size, void* d_ws, size_t ws_size,
                              hipStream_t stream) {
    const float* z_i = (const float*)d_in[0];
    const float* z_j = (const float*)d_in[1];
    float* out = (float*)d_out;
    char* ws = (char*)d_ws;

    unsigned short* zn   = (unsigned short*)ws;                             // 4 MB
    unsigned short* pk2  = (unsigned short*)(ws + (size_t)NROWS * DIM * 2); // 4 MB
    float* part  = (float*)(ws + 2 * (size_t)NROWS * DIM * 2);              // 2 MB
    float* part2 = (float*)(ws + 2 * (size_t)NROWS * DIM * 2
                               + (size_t)NPIECE * NROWS * 4);               // 4 MB
    float* cpart = (float*)(ws + 2 * (size_t)NROWS * DIM * 2
                               + 3 * (size_t)NPIECE * NROWS * 4);           // 32 KB

    normalize_kernel<<<NROWS / 4, 256, 0, stream>>>(z_i, z_j, zn, pk2);
    simloss_kernel<<<NBLK2, 256, 0, stream>>>(pk2, part, part2);
    rowloss_kernel<<<NROWS / 4, 256, 0, stream>>>(zn, part, part2, cpart);
    final_kernel<<<1, 256, 0, stream>>>(cpart, out);
}

// Round 12
// 51.248 us; speedup vs baseline: 1.1309x; 1.1309x over previous
//
#include <hip/hip_runtime.h>
#include <hip/hip_bf16.h>
#include <hip/hip_fp8.h>
#include <math.h>

#define BATCH 4096
#define NROWS 8192
#define DIM 256
#define NP 64                         // 128-row panels
#define NBLK (NP * (NP + 1) / 2)      // 2080 triangular tiles
#define NPIECE (2 * NP)               // 128 denominator pieces per row

// zn scale c with c^2 = 2*log2(e): sim_scaled = c^2*cos = 2*log2e*cos,
// so exp2(sim_scaled) = e^{2 cos} directly. (e4m3 is a float format ->
// relative precision is scale-invariant; same fold works for fp8.)
#define ZN_SCALE 1.698643600577466f   // sqrt(2.8853900817779268)
#define LN2F 0.6931471805599453f

typedef __attribute__((ext_vector_type(4))) float f32x4;

#if defined(__has_builtin)
#if __has_builtin(__builtin_amdgcn_exp2f)
#define EXP2F(x) __builtin_amdgcn_exp2f(x)
#endif
#endif
#ifndef EXP2F
#define EXP2F(x) __expf(LN2F * (x))
#endif

static __device__ __forceinline__ unsigned short f2bf(float x) {
    __hip_bfloat16 h = __float2bfloat16(x);
    return *reinterpret_cast<unsigned short*>(&h);
}
static __device__ __forceinline__ float bf2f(unsigned short u) {
    union { unsigned int i; float f; } x;
    x.i = ((unsigned int)u) << 16;
    return x.f;
}
static __device__ __forceinline__ unsigned char f2fp8(float x) {
    __hip_fp8_e4m3 h(x);              // OCP e4m3fn (gfx950)
    return *reinterpret_cast<unsigned char*>(&h);
}

// ---------------------------------------------------------------------------
// Kernel A: concat + L2-normalize + scale; write row-major bf16 (zn, for the
// positive-pair dot) AND fp8-e4m3 MFMA-fragment-packed (pk8) layouts.
// pk8 granule = one (16-row x 32-k) fp8 fragment = 512 B, lane order for
// v_mfma_f32_16x16x32_fp8_fp8: lane = (k>>3)*16 + (row&15), elems k%8.
// offset(row,e) = ((row>>4)*8 + (e>>5))*512 + (((e&31)>>3)*16 + (row&15))*8
//                 + (e&7)
// ---------------------------------------------------------------------------
__global__ void normalize_kernel(const float* __restrict__ z_i,
                                 const float* __restrict__ z_j,
                                 unsigned short* __restrict__ zn,
                                 unsigned char* __restrict__ pk8) {
    int wid  = (blockIdx.x * blockDim.x + threadIdx.x) >> 6;   // row
    int lane = threadIdx.x & 63;
    if (wid >= NROWS) return;
    const float* src = (wid < BATCH) ? (z_i + (size_t)wid * DIM)
                                     : (z_j + (size_t)(wid - BATCH) * DIM);
    float4 v = reinterpret_cast<const float4*>(src)[lane];
    float ss = v.x * v.x + v.y * v.y + v.z * v.z + v.w * v.w;
#pragma unroll
    for (int m = 1; m < 64; m <<= 1) ss += __shfl_xor(ss, m);
    float inv = ZN_SCALE / fmaxf(sqrtf(ss), 1e-8f);
    ushort4 o;
    o.x = f2bf(v.x * inv);
    o.y = f2bf(v.y * inv);
    o.z = f2bf(v.z * inv);
    o.w = f2bf(v.w * inv);
    reinterpret_cast<ushort4*>(zn + (size_t)wid * DIM)[lane] = o;
    uchar4 o8;
    o8.x = f2fp8(v.x * inv);
    o8.y = f2fp8(v.y * inv);
    o8.z = f2fp8(v.z * inv);
    o8.w = f2fp8(v.w * inv);
    // e = 4*lane: e>>5 = lane>>3; (e&31)>>3 = (lane&7)>>1; e&7 = (lane&1)*4
    size_t off8 = ((size_t)(wid >> 4) * 8 + (lane >> 3)) * 512
                + (size_t)(((lane & 7) >> 1) * 16 + (wid & 15)) * 8
                + (size_t)(lane & 1) * 4;
    *reinterpret_cast<uchar4*>(pk8 + off8) = o8;
}

// ---------------------------------------------------------------------------
// Kernel B: symmetric fused sim-GEMM + sum-of-exp — fp8 operands, NO LDS,
// no barriers. Grid: 2080 tiles, XCD-contiguous swizzle (8 x 260).
// Block = 4 waves (2x2); wave = 64x64 quadrant, acc[4][4] f32x4.
// Fragments straight from pk8 (512 B coalesced dwordx2/lane), 3-buffer
// 2-deep register prefetch. MFMA 16x16x32 fp8 = bf16 rate but HALF the
// operand bytes and HALF the buffer VGPRs -> 3 waves/SIMD.
// Denominator pieces (proven R8/R9 bookkeeping, each slot written once):
//   row pieces: piece q*2+wc for rows of panel p   (all tiles)
//   col pieces: piece p*2+wr for rows of panel q   (p!=q, via symmetry)
// ---------------------------------------------------------------------------
__device__ __forceinline__ void unrank_tile(int t, int& p, int& q) {
    int pp = (int)((129.0f - sqrtf(16641.0f - 8.0f * (float)t)) * 0.5f);
    pp = pp < 0 ? 0 : (pp > 63 ? 63 : pp);
    while (pp > 0 && t < pp * (129 - pp) / 2) --pp;
    while (pp < 63 && t >= (pp + 1) * (128 - pp) / 2) ++pp;
    p = pp;
    q = pp + (t - pp * (129 - pp) / 2);
}

__device__ __forceinline__ void ld8(const char* baseA, const char* baseB,
                                    int s, long long (&A)[4], long long (&B)[4]) {
#pragma unroll
    for (int m = 0; m < 4; ++m)
        A[m] = *(const long long*)(baseA + m * 4096 + s * 512);
#pragma unroll
    for (int n = 0; n < 4; ++n)
        B[n] = *(const long long*)(baseB + n * 4096 + s * 512);
}

__device__ __forceinline__ void mm8(const long long (&A)[4], const long long (&B)[4],
                                    f32x4 (&acc)[4][4]) {
#pragma unroll
    for (int m = 0; m < 4; ++m)
#pragma unroll
        for (int n = 0; n < 4; ++n)
            acc[m][n] = __builtin_amdgcn_mfma_f32_16x16x32_fp8_fp8(
                A[m], B[n], acc[m][n], 0, 0, 0);
}

__global__ __launch_bounds__(256, 3)
void simloss_kernel(const unsigned char* __restrict__ pk8,
                    float* __restrict__ part /* [NPIECE][NROWS] */) {
    int wave = threadIdx.x >> 6;
    int lane = threadIdx.x & 63;
    int lr = lane & 15;                  // fragment col
    int lk = lane >> 4;                  // fragment row group
    int wr = wave >> 1, wc = wave & 1;
    // XCD-contiguous swizzle: 2080 = 8 XCDs x 260 consecutive tiles
    int bt = (int)blockIdx.x;
    int t = (bt & 7) * 260 + (bt >> 3);
    int p, q;
    unrank_tile(t, p, q);

    const char* pkb = (const char*)pk8;
    // row-band rt has 8 granules of 512 B = 4096 B; A bands p*8+wr*4+m
    const char* baseA = pkb + (size_t)(p * 8 + wr * 4) * 4096 + (size_t)lane * 8;
    const char* baseB = pkb + (size_t)(q * 8 + wc * 4) * 4096 + (size_t)lane * 8;

    f32x4 acc[4][4];
#pragma unroll
    for (int m = 0; m < 4; ++m)
#pragma unroll
        for (int n = 0; n < 4; ++n) acc[m][n] = (f32x4){0.f, 0.f, 0.f, 0.f};

    // K = 256 = 8 slices of 32; 3-buffer, 2-deep prefetch, fully unrolled.
    long long Ab[3][4], Bb[3][4];
    ld8(baseA, baseB, 0, Ab[0], Bb[0]);
    ld8(baseA, baseB, 1, Ab[1], Bb[1]);
#pragma unroll
    for (int s = 0; s < 8; ++s) {
        const int cb = s % 3, nb = (s + 2) % 3;
        if (s < 6) ld8(baseA, baseB, s + 2, Ab[nb], Bb[nb]);
        mm8(Ab[cb], Bb[cb], acc);
    }

    // ---- epilogue: exp2, diag-zero, row sums + (p!=q) col sums ----
    // C/D layout (dtype-independent, m121/m124): col=lane&15, row=lk*4+j
    int R0 = p * 128 + wr * 64;
    int C0 = q * 128 + wc * 64;
    float dacc[4][4];
#pragma unroll
    for (int m = 0; m < 4; ++m)
#pragma unroll
        for (int j = 0; j < 4; ++j) dacc[m][j] = 0.f;
    float cacc[4] = {0.f, 0.f, 0.f, 0.f};

#pragma unroll
    for (int m = 0; m < 4; ++m) {
        int gr = R0 + m * 16;
#pragma unroll
        for (int n = 0; n < 4; ++n) {
            int gc = C0 + n * 16;
            bool diagf = (gr == gc);      // uniform per fragment
            float cs_ = 0.f;
#pragma unroll
            for (int j = 0; j < 4; ++j) {
                float e = EXP2F(acc[m][n][j]);
                if (diagf && lr == lk * 4 + j) e = 0.0f;
                dacc[m][j] += e;
                cs_ += e;
            }
            cacc[n] += cs_;
        }
    }

    // row pieces: reduce over 16 col-lanes (lr); lanes lr==0 write (nt)
#pragma unroll
    for (int m = 0; m < 4; ++m)
#pragma unroll
        for (int j = 0; j < 4; ++j) {
            float v = dacc[m][j];
            v += __shfl_xor(v, 1);
            v += __shfl_xor(v, 2);
            v += __shfl_xor(v, 4);
            v += __shfl_xor(v, 8);
            if (lr == 0)
                __builtin_nontemporal_store(v,
                    &part[(size_t)(q * 2 + wc) * NROWS + R0 + m * 16 + lk * 4 + j]);
        }
    // col pieces: reduce over the 4 lk groups; lanes lk==0 (0..15) write (nt)
    if (p != q) {
#pragma unroll
        for (int n = 0; n < 4; ++n) {
            float c = cacc[n];
            c += __shfl_xor(c, 16);
            c += __shfl_xor(c, 32);
            if (lk == 0)
                __builtin_nontemporal_store(c,
                    &part[(size_t)(p * 2 + wr) * NROWS + C0 + n * 16 + lr]);
        }
    }
}

// ---------------------------------------------------------------------------
// Kernel C: per-row loss: log(sum of 128 pieces) - pos_dot*ln2
// One row per wave; part (4 MB) is L2/L3-resident.
// ---------------------------------------------------------------------------
__global__ void rowloss_kernel(const unsigned short* __restrict__ zn,
                               const float* __restrict__ part,
                               float* __restrict__ cpart /* [NROWS] */) {
    int wave = threadIdx.x >> 6;
    int lane = threadIdx.x & 63;
    int r = blockIdx.x * 4 + wave;
    ushort4 za = reinterpret_cast<const ushort4*>(zn + (size_t)r * DIM)[lane];
    ushort4 zb = reinterpret_cast<const ushort4*>(zn + (size_t)(r ^ BATCH) * DIM)[lane];
    float dot = bf2f(za.x) * bf2f(zb.x) + bf2f(za.y) * bf2f(zb.y) +
                bf2f(za.z) * bf2f(zb.z) + bf2f(za.w) * bf2f(zb.w);
#pragma unroll
    for (int m = 1; m < 64; m <<= 1) dot += __shfl_xor(dot, m);
    float den = part[(size_t)lane * NROWS + r]
              + part[(size_t)(lane + 64) * NROWS + r];
#pragma unroll
    for (int m = 1; m < 64; m <<= 1) den += __shfl_xor(den, m);
    if (lane == 0) cpart[r] = logf(den) - dot * LN2F;
}

// ---------------------------------------------------------------------------
// Kernel D: final reduction of 8192 row losses -> scalar loss / n
// ---------------------------------------------------------------------------
__global__ void final_kernel(const float* __restrict__ cpart,
                             float* __restrict__ out) {
    int lane = threadIdx.x & 63;
    int wave = threadIdx.x >> 6;
    double v = 0.0;
#pragma unroll
    for (int k = 0; k < 32; ++k)
        v += (double)cpart[threadIdx.x + k * 256];
#pragma unroll
    for (int m = 1; m < 64; m <<= 1) v += __shfl_xor(v, m);
    __shared__ double red[4];
    if (lane == 0) red[wave] = v;
    __syncthreads();
    if (threadIdx.x == 0)
        out[0] = (float)((red[0] + red[1] + red[2] + red[3]) / (double)NROWS);
}

// ---------------------------------------------------------------------------
extern "C" void kernel_launch(void* const* d_in, const int* in_sizes, int n_in,
                              void* d_out, int out_size, void* d_ws, size_t ws_size,
                              hipStream_t stream) {
    const float* z_i = (const float*)d_in[0];
    const float* z_j = (const float*)d_in[1];
    float* out = (float*)d_out;
    char* ws = (char*)d_ws;

    unsigned short* zn  = (unsigned short*)ws;                             // 4 MB
    unsigned char*  pk8 = (unsigned char*)(ws + (size_t)NROWS * DIM * 2);  // 2 MB
    float* part  = (float*)(ws + (size_t)NROWS * DIM * 2
                               + (size_t)NROWS * DIM);                     // 4 MB
    float* cpart = (float*)(ws + (size_t)NROWS * DIM * 2
                               + (size_t)NROWS * DIM
                               + (size_t)NPIECE * NROWS * 4);              // 32 KB

    normalize_kernel<<<NROWS / 4, 256, 0, stream>>>(z_i, z_j, zn, pk8);
    simloss_kernel<<<NBLK, 256, 0, stream>>>(pk8, part);
    rowloss_kernel<<<NROWS / 4, 256, 0, stream>>>(zn, part, cpart);
    final_kernel<<<1, 256, 0, stream>>>(cpart, out);
}